// Round 11
// baseline (239.418 us; speedup 1.0000x reference)
//
#include <hip/hip_runtime.h>
#include <math.h>

#define NPT 2048
#define KNN 20

typedef const float* fp;
typedef __attribute__((ext_vector_type(4))) float f32x4;
typedef __attribute__((ext_vector_type(8))) short s16x8;

// round-to-nearest-even f32 -> bf16 bits (inputs are finite)
__device__ __forceinline__ ushort f2bf_rne(float v) {
    unsigned u = __float_as_uint(v);
    unsigned r = u + 0x7FFFu + ((u >> 16) & 1u);
    return (ushort)(r >> 16);
}
__device__ __forceinline__ float bfbits2f(ushort h) {
    return __uint_as_float(((unsigned)h) << 16);
}
__device__ __forceinline__ s16x8 ldfrag(const ushort* p) {
    union { uint4 u; s16x8 s; } cv;
    cv.u = *reinterpret_cast<const uint4*>(p);
    return cv.s;
}
// 8 consecutive f32 -> bf16 hi/lo fragment pair (in-register fragify)
__device__ __forceinline__ void f8_hilo(const float* row, s16x8* hi, s16x8* lo) {
    float4 f0 = *reinterpret_cast<const float4*>(row);
    float4 f1 = *reinterpret_cast<const float4*>(row + 4);
    float f[8] = {f0.x, f0.y, f0.z, f0.w, f1.x, f1.y, f1.z, f1.w};
    union { ushort u[8]; s16x8 s; } H, L;
    #pragma unroll
    for (int j = 0; j < 8; j++) {
        ushort h = f2bf_rne(f[j]);
        H.u[j] = h;
        L.u[j] = f2bf_rne(f[j] - bfbits2f(h));
    }
    *hi = H.s; *lo = L.s;
}

// ---------------------------------------------------------------------------
// prep_all: blocks [0,256) = fragify x + xx; blocks [256,835) = weight frags
//   (q/k/v K=128; wc=[w1x | w1a@wm] K=256 on-the-fly; w2 K=256), b1p, stats=0.
// ---------------------------------------------------------------------------
__global__ __launch_bounds__(256) void prep_all(
    fp xbf, fp wq, fp wk, fp wv, fp wm, fp w1, fp w2, fp bm, fp b1,
    float* xx, ushort* xhiF, ushort* xloF,
    ushort* wqFhi, ushort* wqFlo, ushort* wkFhi, ushort* wkFlo,
    ushort* wvFhi, ushort* wvFlo,
    ushort* wcFhi, ushort* wcFlo, ushort* w2Fhi, ushort* w2Flo,
    float* b1p, float* stats) {
    int t = threadIdx.x;
    if (blockIdx.x < 256) {                 // ---- x frags + xx ----
        __shared__ float xs[16][129];
        __shared__ float xpart[16][17];
        int p0 = blockIdx.x * 16;
        int b = p0 >> 11, n0 = p0 & 2047;
        fp xb = xbf + (size_t)b * 128 * NPT;
        {
            int c = t >> 1, half = t & 1;
            float4 f0 = *reinterpret_cast<const float4*>(xb + (size_t)c * NPT + n0 + half * 8);
            float4 f1 = *reinterpret_cast<const float4*>(xb + (size_t)c * NPT + n0 + half * 8 + 4);
            xs[half * 8 + 0][c] = f0.x; xs[half * 8 + 1][c] = f0.y;
            xs[half * 8 + 2][c] = f0.z; xs[half * 8 + 3][c] = f0.w;
            xs[half * 8 + 4][c] = f1.x; xs[half * 8 + 5][c] = f1.y;
            xs[half * 8 + 6][c] = f1.z; xs[half * 8 + 7][c] = f1.w;
        }
        __syncthreads();
        int p = t & 15, g = t >> 4, c0 = g * 8;
        float f[8];
        #pragma unroll
        for (int j = 0; j < 8; j++) f[j] = xs[p][c0 + j];
        float ps = 0.f;
        #pragma unroll
        for (int j = 0; j < 8; j++) ps += f[j] * f[j];
        xpart[p][g] = ps;
        union { ushort u[8]; uint4 q; } H, L;
        #pragma unroll
        for (int j = 0; j < 8; j++) {
            ushort hi = f2bf_rne(f[j]);
            H.u[j] = hi;
            L.u[j] = f2bf_rne(f[j] - bfbits2f(hi));
        }
        size_t off = ((size_t)blockIdx.x * 4 + (c0 >> 5)) * 512
                   + (size_t)(((((c0 >> 3) & 3) * 16) + p) * 8);
        *reinterpret_cast<uint4*>(xhiF + off) = H.q;
        *reinterpret_cast<uint4*>(xloF + off) = L.q;
        __syncthreads();
        if (t < 16) {
            float s = 0.f;
            #pragma unroll
            for (int gg = 0; gg < 16; gg++) s += xpart[t][gg];
            xx[p0 + t] = s;
        }
        return;
    }
    int wid = (blockIdx.x - 256) * 256 + t;
    if (wid < 49152) {                      // q/k/v frags (K=128)
        int which = wid >> 14, e = wid & 16383;
        int lane = (e >> 3) & 63, j = e & 7, kk = (e >> 9) & 3, nt = e >> 11;
        int n = nt * 16 + (lane & 15);
        int k = kk * 32 + (lane >> 4) * 8 + j;
        fp src = which == 0 ? wq : which == 1 ? wk : wv;
        float v = src[n * 128 + k];
        ushort hi = f2bf_rne(v);
        (which == 0 ? wqFhi : which == 1 ? wkFhi : wvFhi)[e] = hi;
        (which == 0 ? wqFlo : which == 1 ? wkFlo : wvFlo)[e] = f2bf_rne(v - bfbits2f(hi));
    } else if (wid < 114688) {              // wc frags (N=256, K=256)
        int e = wid - 49152;
        int j = e & 7, lane = (e >> 3) & 63, kk = (e >> 9) & 7, nt = e >> 12;
        int n = nt * 16 + (lane & 15);
        int k = kk * 32 + (lane >> 4) * 8 + j;
        float v;
        if (k < 128) {
            v = w1[n * 256 + k];
        } else {                            // W[n][k-128] = w1a@wm on the fly
            int c = k - 128;
            float s = 0.f;
            for (int i = 0; i < 128; i += 4) {
                float4 wr = *reinterpret_cast<const float4*>(w1 + n * 256 + 128 + i);
                s += wr.x * wm[(i + 0) * 128 + c];
                s += wr.y * wm[(i + 1) * 128 + c];
                s += wr.z * wm[(i + 2) * 128 + c];
                s += wr.w * wm[(i + 3) * 128 + c];
            }
            v = s;
        }
        ushort hi = f2bf_rne(v);
        wcFhi[e] = hi;
        wcFlo[e] = f2bf_rne(v - bfbits2f(hi));
    } else if (wid < 147456) {              // w2 frags (N=128, K=256)
        int e = wid - 114688;
        int j = e & 7, lane = (e >> 3) & 63, kk = (e >> 9) & 7, nt = e >> 12;
        int n = nt * 16 + (lane & 15);
        int k = kk * 32 + (lane >> 4) * 8 + j;
        float v = w2[n * 256 + k];
        ushort hi = f2bf_rne(v);
        w2Fhi[e] = hi;
        w2Flo[e] = f2bf_rne(v - bfbits2f(hi));
    } else if (wid < 147712) {              // b1p = b1 + w1a@bm
        int o = wid - 147456;
        float s = b1[o];
        for (int i = 0; i < 128; i++)
            s += w1[o * 256 + 128 + i] * bm[i];
        b1p[o] = s;
    } else {                                // BN stats zero (512)
        stats[wid - 147712] = 0.0f;
    }
}

// ---------------------------------------------------------------------------
// gemm_all: blocks [0,384) = qkv GEMM; [384,1408) = key slab 0;
//           [1408,2432) = key slab 1. All hi/lo bf16 MFMA.
// ---------------------------------------------------------------------------
__global__ __launch_bounds__(256) void gemm_all(
    const ushort* xhiF, const ushort* xloF, const float* xx,
    const ushort* wqFhi, const ushort* wqFlo,
    const ushort* wkFhi, const ushort* wkFlo,
    const ushort* wvFhi, const ushort* wvFlo,
    fp bq, fp bk, fp bv, float* qT, float* kT, float* vT,
    float* key0, float* key1) {
    int t = threadIdx.x, wvi = t >> 6, lane = t & 63;
    if (blockIdx.x < 384) {                 // ---- qkv ----
        int gw = blockIdx.x * 4 + wvi;      // 0..1535
        int rt = gw / 6, rem = gw - rt * 6;
        int mat = rem >> 1, hf = rem & 1;
        const ushort* whi = mat == 0 ? wqFhi : mat == 1 ? wkFhi : wvFhi;
        const ushort* wlo = mat == 0 ? wqFlo : mat == 1 ? wkFlo : wvFlo;
        fp bias    = mat == 0 ? bq : mat == 1 ? bk : bv;
        float* out = mat == 0 ? qT : mat == 1 ? kT : vT;
        f32x4 acc[4];
        #pragma unroll
        for (int j = 0; j < 4; j++) acc[j] = (f32x4){0.f, 0.f, 0.f, 0.f};
        for (int kk = 0; kk < 4; kk++) {
            s16x8 ahi = ldfrag(xhiF + ((size_t)(rt * 4 + kk)) * 512 + lane * 8);
            s16x8 alo = ldfrag(xloF + ((size_t)(rt * 4 + kk)) * 512 + lane * 8);
            #pragma unroll
            for (int j = 0; j < 4; j++) {
                int nt = hf * 4 + j;
                s16x8 bhi = ldfrag(whi + ((size_t)(nt * 4 + kk)) * 512 + lane * 8);
                s16x8 blo = ldfrag(wlo + ((size_t)(nt * 4 + kk)) * 512 + lane * 8);
                acc[j] = __builtin_amdgcn_mfma_f32_16x16x32_bf16(ahi, bhi, acc[j], 0, 0, 0);
                acc[j] = __builtin_amdgcn_mfma_f32_16x16x32_bf16(alo, bhi, acc[j], 0, 0, 0);
                acc[j] = __builtin_amdgcn_mfma_f32_16x16x32_bf16(ahi, blo, acc[j], 0, 0, 0);
            }
        }
        int cl = lane & 15, quad = lane >> 4, p0 = rt * 16;
        #pragma unroll
        for (int j = 0; j < 4; j++) {
            int o = hf * 64 + j * 16 + cl;
            float bvv = bias[o];
            #pragma unroll
            for (int r = 0; r < 4; r++)
                out[(size_t)(p0 + quad * 4 + r) * 128 + o] = acc[j][r] + bvv;
        }
        return;
    }
    // ---- key GEMM ----
    int slab = (blockIdx.x >= 1408) ? 1 : 0;
    int lb = blockIdx.x - 384 - slab * 1024;
    int gw = lb * 4 + wvi;                  // 0..4095
    int rtl = gw >> 5, cs = gw & 31;
    int b = slab;
    int rt = slab * 128 + rtl;
    float* key = slab ? key1 : key0;

    f32x4 acc[4];
    #pragma unroll
    for (int j = 0; j < 4; j++) acc[j] = (f32x4){0.f, 0.f, 0.f, 0.f};
    for (int kk = 0; kk < 4; kk++) {
        s16x8 ahi = ldfrag(xhiF + ((size_t)(rt * 4 + kk)) * 512 + lane * 8);
        s16x8 alo = ldfrag(xloF + ((size_t)(rt * 4 + kk)) * 512 + lane * 8);
        #pragma unroll
        for (int j = 0; j < 4; j++) {
            int ct = b * 128 + cs * 4 + j;
            s16x8 bhi = ldfrag(xhiF + ((size_t)(ct * 4 + kk)) * 512 + lane * 8);
            s16x8 blo = ldfrag(xloF + ((size_t)(ct * 4 + kk)) * 512 + lane * 8);
            acc[j] = __builtin_amdgcn_mfma_f32_16x16x32_bf16(ahi, bhi, acc[j], 0, 0, 0);
            acc[j] = __builtin_amdgcn_mfma_f32_16x16x32_bf16(alo, bhi, acc[j], 0, 0, 0);
            acc[j] = __builtin_amdgcn_mfma_f32_16x16x32_bf16(ahi, blo, acc[j], 0, 0, 0);
        }
    }
    int cl = lane & 15, quad = lane >> 4;
    #pragma unroll
    for (int j = 0; j < 4; j++) {
        int col = cs * 64 + j * 16 + cl;
        float xxv = xx[b * 2048 + col];
        #pragma unroll
        for (int r = 0; r < 4; r++)
            key[(size_t)(rtl * 16 + quad * 4 + r) * 2048 + col] = 2.0f * acc[j][r] - xxv;
    }
}

// ---------------------------------------------------------------------------
// k2b1: per-QUARTER-row top-20 (exact superset of global top-20 members).
//       Wave = 512 cols (8 slots/lane). 16384 waves total.
// ---------------------------------------------------------------------------
#define MERGE(off) { float ov = __shfl_xor(bv, off); int oi = __shfl_xor(bi, off); \
                     if (ov > bv || (ov == bv && oi < bi)) { bv = ov; bi = oi; } }

__global__ __launch_bounds__(256) void k2b1(
    const float* key0, const float* key1, float* candV, int* candI) {
    int t = threadIdx.x, wvi = t >> 6, lane = t & 63;
    int gw = blockIdx.x * 4 + wvi;          // 0..16383
    int row = gw >> 2, qr = gw & 3;
    int slab = row >> 11, rowl = row & 2047;
    const float* key = slab ? key1 : key0;
    const float4* kr = reinterpret_cast<const float4*>(key + (size_t)rowl * 2048 + qr * 512);
    float rv[8];
    #pragma unroll
    for (int j = 0; j < 2; j++) {
        float4 v = kr[j * 64 + lane];
        rv[j * 4 + 0] = v.x; rv[j * 4 + 1] = v.y;
        rv[j * 4 + 2] = v.z; rv[j * 4 + 3] = v.w;
    }
    unsigned removed = 0u;
    for (int iter = 0; iter < KNN; iter++) {
        float bv = -3.4e38f; int bi = 0;
        #pragma unroll
        for (int sl = 0; sl < 8; sl++) {    // ascending col per lane: strict >
            bool live = ((removed >> sl) & 1u) == 0u;
            if (live && rv[sl] > bv) {
                bv = rv[sl];
                bi = qr * 512 + (sl >> 2) * 256 + lane * 4 + (sl & 3);
            }
        }
        MERGE(32) MERGE(16) MERGE(8) MERGE(4) MERGE(2) MERGE(1)
        if (lane == 0) {
            candV[(size_t)row * 80 + qr * 20 + iter] = bv;
            candI[(size_t)row * 80 + qr * 20 + iter] = bi & 2047;
        }
        if (((bi >> 2) & 63) == lane)       // owner masks slot
            removed |= 1u << (((bi >> 8) & 1) * 4 + (bi & 3));
    }
}

// ---------------------------------------------------------------------------
// k2b2: merge 80 candidates/row -> final top-20 (same comparator => same
//       order & membership as monolithic top-20).
// ---------------------------------------------------------------------------
__global__ __launch_bounds__(256) void k2b2(
    const float* candV, const int* candI, int* idxbuf) {
    int t = threadIdx.x, wvi = t >> 6, lane = t & 63;
    int row = blockIdx.x * 4 + wvi;         // 0..4095
    const float* cv = candV + (size_t)row * 80;
    const int*   ci = candI + (size_t)row * 80;
    float rv[2]; int ridx[2];
    rv[0] = cv[lane]; ridx[0] = ci[lane];
    bool v1 = lane < 16;
    rv[1]   = v1 ? cv[64 + lane] : -3.4e38f;
    ridx[1] = v1 ? ci[64 + lane] : 0x7FFFFFFF;
    unsigned removed = 0u;
    for (int iter = 0; iter < KNN; iter++) {
        float bv = -3.4e38f; int bi = 0x7FFFFFFF;
        #pragma unroll
        for (int sl = 0; sl < 2; sl++) {
            bool live = ((removed >> sl) & 1u) == 0u;
            if (live && (rv[sl] > bv || (rv[sl] == bv && ridx[sl] < bi))) {
                bv = rv[sl]; bi = ridx[sl];
            }
        }
        MERGE(32) MERGE(16) MERGE(8) MERGE(4) MERGE(2) MERGE(1)
        if (lane == 0) idxbuf[(size_t)row * KNN + iter] = bi & 2047;
        #pragma unroll
        for (int sl = 0; sl < 2; sl++)      // indices unique: safe removal
            if (ridx[sl] == bi) removed |= 1u << sl;
    }
}

// ---------------------------------------------------------------------------
// k3: sparse mutual-KNN attention, 2 points/block; inline mutuality scan.
// ---------------------------------------------------------------------------
__global__ __launch_bounds__(256) void k3_attn(
    fp qT, fp kT, fp vT, const int* idxbuf, float* avT) {
    __shared__ float sbuf[2][KNN * 4];
    __shared__ int   mlist[2][KNN];
    __shared__ int   cnt_s[2];
    int tt = threadIdx.x;
    int half = tt >> 7, t = tt & 127;
    int p = blockIdx.x * 2 + half;
    int b = p >> 11, n = p & 2047;
    int bbase = b * NPT;
    int h = t >> 5;

    if ((tt >> 6) == half * 2) {
        int lane = tt & 63;
        bool fl = false; int m = 0;
        if (lane < KNN) {
            m = idxbuf[(size_t)p * KNN + lane] & 2047;
            const int4* mrow = reinterpret_cast<const int4*>(idxbuf + (size_t)(bbase + m) * KNN);
            int4 r0 = mrow[0], r1 = mrow[1], r2 = mrow[2], r3 = mrow[3], r4 = mrow[4];
            fl = (r0.x == n) || (r0.y == n) || (r0.z == n) || (r0.w == n)
              || (r1.x == n) || (r1.y == n) || (r1.z == n) || (r1.w == n)
              || (r2.x == n) || (r2.y == n) || (r2.z == n) || (r2.w == n)
              || (r3.x == n) || (r3.y == n) || (r3.z == n) || (r3.w == n)
              || (r4.x == n) || (r4.y == n) || (r4.z == n) || (r4.w == n);
        }
        unsigned long long mask = __ballot(fl);
        int pos = __popcll(mask & ((1ull << lane) - 1ull));
        if (fl) mlist[half][pos] = m;
        if (lane == 0) cnt_s[half] = (int)__popcll(mask);
    }
    __syncthreads();

    int cnt = cnt_s[half];
    float qv = qT[(size_t)p * 128 + t];
    for (int jj = 0; jj < cnt; jj++) {
        int m = mlist[half][jj];
        float prod = qv * kT[(size_t)(bbase + m) * 128 + t];
        prod += __shfl_xor(prod, 16);
        prod += __shfl_xor(prod, 8);
        prod += __shfl_xor(prod, 4);
        prod += __shfl_xor(prod, 2);
        prod += __shfl_xor(prod, 1);
        if ((t & 31) == 0) sbuf[half][jj * 4 + h] = prod * 0.17677669529663687f;
    }
    __syncthreads();

    float mx = -3.4e38f;
    for (int j = 0; j < cnt; j++) mx = fmaxf(mx, sbuf[half][j * 4 + h]);
    float den = 0.f;
    for (int j = 0; j < cnt; j++) den += expf(sbuf[half][j * 4 + h] - mx);
    float inv = (cnt > 0) ? (1.0f / den) : 0.0f;
    float acc = 0.f;
    for (int j = 0; j < cnt; j++) {
        float pw = expf(sbuf[half][j * 4 + h] - mx) * inv;
        acc += pw * vT[(size_t)(bbase + mlist[half][j]) * 128 + t];
    }
    avT[(size_t)p * 128 + t] = acc;
}

// ---------------------------------------------------------------------------
// k4b: h = w1x@x + W@av + b1p via MFMA (K=256); epilogue: hbuf + BN stats.
// ---------------------------------------------------------------------------
__global__ __launch_bounds__(256) void k4b_h(
    const ushort* xhiF, const ushort* xloF, const float* avT,
    const ushort* wcFhi, const ushort* wcFlo,
    const float* b1p, float* hbuf, float* stats) {
    int t = threadIdx.x, cs = t >> 6, lane = t & 63;
    int rt = blockIdx.x;                    // 0..255
    int p0 = rt * 16;

    f32x4 acc[4];
    #pragma unroll
    for (int j = 0; j < 4; j++) acc[j] = (f32x4){0.f, 0.f, 0.f, 0.f};

    for (int kk = 0; kk < 8; kk++) {
        s16x8 ahi, alo;
        if (kk < 4) {
            ahi = ldfrag(xhiF + ((size_t)(rt * 4 + kk)) * 512 + lane * 8);
            alo = ldfrag(xloF + ((size_t)(rt * 4 + kk)) * 512 + lane * 8);
        } else {
            const float* arow = avT + (size_t)(p0 + (lane & 15)) * 128
                              + (kk - 4) * 32 + (lane >> 4) * 8;
            f8_hilo(arow, &ahi, &alo);
        }
        #pragma unroll
        for (int j = 0; j < 4; j++) {
            int nt = cs * 4 + j;
            s16x8 bhi = ldfrag(wcFhi + ((size_t)(nt * 8 + kk)) * 512 + lane * 8);
            s16x8 blo = ldfrag(wcFlo + ((size_t)(nt * 8 + kk)) * 512 + lane * 8);
            acc[j] = __builtin_amdgcn_mfma_f32_16x16x32_bf16(ahi, bhi, acc[j], 0, 0, 0);
            acc[j] = __builtin_amdgcn_mfma_f32_16x16x32_bf16(alo, bhi, acc[j], 0, 0, 0);
            acc[j] = __builtin_amdgcn_mfma_f32_16x16x32_bf16(ahi, blo, acc[j], 0, 0, 0);
        }
    }

    int cl = lane & 15, quad = lane >> 4;
    #pragma unroll
    for (int j = 0; j < 4; j++) {
        int o = cs * 64 + j * 16 + cl;
        float bb = b1p[o];
        float s = 0.f, s2 = 0.f;
        #pragma unroll
        for (int r = 0; r < 4; r++) {
            float v = acc[j][r] + bb;
            hbuf[(size_t)(p0 + quad * 4 + r) * 256 + o] = v;
            s += v; s2 += v * v;
        }
        s  += __shfl_xor(s, 16);  s  += __shfl_xor(s, 32);
        s2 += __shfl_xor(s2, 16); s2 += __shfl_xor(s2, 32);
        if (quad == 0) {
            atomicAdd(&stats[o], s);
            atomicAdd(&stats[256 + o], s2);
        }
    }
}

// ---------------------------------------------------------------------------
// k5b: out = w2@relu(BN(h)) + b2 + x via MFMA (K=256), BN in-register.
// ---------------------------------------------------------------------------
__global__ __launch_bounds__(256) void k5b_out(
    const float* hbuf, const float* stats, fp gamma, fp beta,
    const ushort* w2Fhi, const ushort* w2Flo,
    fp b2, fp xbf, float* out) {
    int t = threadIdx.x, wvi = t >> 6, lane = t & 63;
    int rt = blockIdx.x;                    // 0..255
    int p0 = rt * 16;

    f32x4 acc[2];
    acc[0] = (f32x4){0.f, 0.f, 0.f, 0.f};
    acc[1] = (f32x4){0.f, 0.f, 0.f, 0.f};

    for (int kk = 0; kk < 8; kk++) {
        int c0 = kk * 32 + (lane >> 4) * 8;
        const float* hrow = hbuf + (size_t)(p0 + (lane & 15)) * 256 + c0;
        float4 f0 = *reinterpret_cast<const float4*>(hrow);
        float4 f1 = *reinterpret_cast<const float4*>(hrow + 4);
        float4 s0 = *reinterpret_cast<const float4*>(stats + c0);
        float4 s1 = *reinterpret_cast<const float4*>(stats + c0 + 4);
        float4 q0 = *reinterpret_cast<const float4*>(stats + 256 + c0);
        float4 q1 = *reinterpret_cast<const float4*>(stats + 256 + c0 + 4);
        float4 g0 = *reinterpret_cast<const float4*>(gamma + c0);
        float4 g1 = *reinterpret_cast<const float4*>(gamma + c0 + 4);
        float4 e0 = *reinterpret_cast<const float4*>(beta + c0);
        float4 e1 = *reinterpret_cast<const float4*>(beta + c0 + 4);
        float f[8] = {f0.x, f0.y, f0.z, f0.w, f1.x, f1.y, f1.z, f1.w};
        float sm[8] = {s0.x, s0.y, s0.z, s0.w, s1.x, s1.y, s1.z, s1.w};
        float sq[8] = {q0.x, q0.y, q0.z, q0.w, q1.x, q1.y, q1.z, q1.w};
        float gm[8] = {g0.x, g0.y, g0.z, g0.w, g1.x, g1.y, g1.z, g1.w};
        float bt[8] = {e0.x, e0.y, e0.z, e0.w, e1.x, e1.y, e1.z, e1.w};
        union { ushort u[8]; s16x8 s; } H, L;
        #pragma unroll
        for (int j = 0; j < 8; j++) {
            float mu  = sm[j] * (1.0f / 4096.0f);
            float var = fmaxf(sq[j] * (1.0f / 4096.0f) - mu * mu, 0.0f);
            float a    = gm[j] / sqrtf(var + 1e-5f);
            float cadd = bt[j] - mu * a;
            float v = fmaxf(f[j] * a + cadd, 0.0f);
            ushort hi = f2bf_rne(v);
            H.u[j] = hi;
            L.u[j] = f2bf_rne(v - bfbits2f(hi));
        }
        s16x8 ahi = H.s, alo = L.s;
        #pragma unroll
        for (int jj = 0; jj < 2; jj++) {
            int nt = wvi * 2 + jj;
            s16x8 bhi = ldfrag(w2Fhi + ((size_t)(nt * 8 + kk)) * 512 + lane * 8);
            s16x8 blo = ldfrag(w2Flo + ((size_t)(nt * 8 + kk)) * 512 + lane * 8);
            acc[jj] = __builtin_amdgcn_mfma_f32_16x16x32_bf16(ahi, bhi, acc[jj], 0, 0, 0);
            acc[jj] = __builtin_amdgcn_mfma_f32_16x16x32_bf16(alo, bhi, acc[jj], 0, 0, 0);
            acc[jj] = __builtin_amdgcn_mfma_f32_16x16x32_bf16(ahi, blo, acc[jj], 0, 0, 0);
        }
    }
    int cl = lane & 15, quad = lane >> 4;
    int b = p0 >> 11, n0 = p0 & 2047;
    #pragma unroll
    for (int jj = 0; jj < 2; jj++) {
        int o = (wvi * 2 + jj) * 16 + cl;
        float bb = b2[o];
        size_t base = (size_t)b * 128 * NPT + (size_t)o * NPT + n0 + quad * 4;
        float4 xv = *reinterpret_cast<const float4*>(xbf + base);
        float4 ov;
        ov.x = acc[jj][0] + bb + xv.x;
        ov.y = acc[jj][1] + bb + xv.y;
        ov.z = acc[jj][2] + bb + xv.z;
        ov.w = acc[jj][3] + bb + xv.w;
        *reinterpret_cast<float4*>(out + base) = ov;
    }
}

// ---------------------------------------------------------------------------
// Workspace layout (47,599,616 B; observed ws ≈ 268 MB):
//   0        qT 2MB [gemm->k3]   <- hbuf 4MB (k4b->k5b) aliases qT+kT
//   2097152  kT 2MB | 4194304 vT 2MB | 6291456 avT 2MB [k3->k4b]
//   8388608  xx 16KB | 8404992 idxb 320KB | 8732672 stats 2KB | 8734720 b1p 2KB
//   8736768  wq/wk/wv frags 6x32KB
//   8933376  wcFhi/lo 2x128KB | 9195520 w2Fhi/lo 2x64KB
//   9326592  xhiF 1MB | 10375168 xloF 1MB
//   11423744 key0 16MB | 28200960 key1 16MB
//   44978176 candV 1.31MB | 46288896 candI 1.31MB  [k2b1->k2b2]
// ---------------------------------------------------------------------------
#define WS_FULL 47599616u

extern "C" void kernel_launch(void* const* d_in, const int* in_sizes, int n_in,
                              void* d_out, int out_size, void* d_ws, size_t ws_size,
                              hipStream_t stream) {
    fp desc1 = (fp)d_in[0];
    fp wq = (fp)d_in[1];  fp bq = (fp)d_in[2];
    fp wk = (fp)d_in[3];  fp bk = (fp)d_in[4];
    fp wv = (fp)d_in[5];  fp bv = (fp)d_in[6];
    fp wm = (fp)d_in[7];  fp bm = (fp)d_in[8];
    fp w1 = (fp)d_in[9];  fp b1 = (fp)d_in[10];
    fp gamma = (fp)d_in[11]; fp beta = (fp)d_in[12];
    fp w2 = (fp)d_in[13]; fp b2 = (fp)d_in[14];

    if (ws_size < (size_t)WS_FULL) return;  // all-zero out => ws too small

    char* ws = (char*)d_ws;
    float*  qT    = (float*) (ws + 0);
    float*  kT    = (float*) (ws + 2097152);
    float*  vT    = (float*) (ws + 4194304);
    float*  avT   = (float*) (ws + 6291456);
    float*  xx    = (float*) (ws + 8388608);
    int*    idxb  = (int*)   (ws + 8404992);
    float*  stats = (float*) (ws + 8732672);
    float*  b1p   = (float*) (ws + 8734720);
    ushort* wqFhi = (ushort*)(ws + 8736768);
    ushort* wqFlo = (ushort*)(ws + 8769536);
    ushort* wkFhi = (ushort*)(ws + 8802304);
    ushort* wkFlo = (ushort*)(ws + 8835072);
    ushort* wvFhi = (ushort*)(ws + 8867840);
    ushort* wvFlo = (ushort*)(ws + 8900608);
    ushort* wcFhi = (ushort*)(ws + 8933376);
    ushort* wcFlo = (ushort*)(ws + 9064448);
    ushort* w2Fhi = (ushort*)(ws + 9195520);
    ushort* w2Flo = (ushort*)(ws + 9261056);
    ushort* xhiF  = (ushort*)(ws + 9326592);
    ushort* xloF  = (ushort*)(ws + 10375168);
    float*  key0  = (float*) (ws + 11423744);
    float*  key1  = (float*) (ws + 28200960);
    float*  candV = (float*) (ws + 44978176);
    int*    candI = (int*)   (ws + 46288896);
    float*  hbuf  = (float*) (ws + 0);      // aliases qT+kT (dead after k3)

    prep_all<<<835, 256, 0, stream>>>(desc1, wq, wk, wv, wm, w1, w2, bm, b1,
                                      xx, xhiF, xloF,
                                      wqFhi, wqFlo, wkFhi, wkFlo, wvFhi, wvFlo,
                                      wcFhi, wcFlo, w2Fhi, w2Flo, b1p, stats);
    gemm_all<<<2432, 256, 0, stream>>>(xhiF, xloF, xx,
                                       wqFhi, wqFlo, wkFhi, wkFlo, wvFhi, wvFlo,
                                       bq, bk, bv, qT, kT, vT, key0, key1);
    k2b1<<<4096, 256, 0, stream>>>(key0, key1, candV, candI);
    k2b2<<<1024, 256, 0, stream>>>(candV, candI, idxb);
    k3_attn<<<2048, 256, 0, stream>>>(qT, kT, vT, idxb, avT);
    k4b_h<<<256, 256, 0, stream>>>(xhiF, xloF, avT, wcFhi, wcFlo,
                                   b1p, hbuf, stats);
    k5b_out<<<256, 256, 0, stream>>>(hbuf, stats, gamma, beta, w2Fhi, w2Flo,
                                     b2, desc1, (float*)d_out);
}

// Round 12
// 194.867 us; speedup vs baseline: 1.2286x; 1.2286x over previous
//
#include <hip/hip_runtime.h>
#include <math.h>

#define NPT 2048
#define KNN 20

typedef const float* fp;
typedef __attribute__((ext_vector_type(4))) float f32x4;
typedef __attribute__((ext_vector_type(8))) short s16x8;

// round-to-nearest-even f32 -> bf16 bits (inputs are finite)
__device__ __forceinline__ ushort f2bf_rne(float v) {
    unsigned u = __float_as_uint(v);
    unsigned r = u + 0x7FFFu + ((u >> 16) & 1u);
    return (ushort)(r >> 16);
}
__device__ __forceinline__ float bfbits2f(ushort h) {
    return __uint_as_float(((unsigned)h) << 16);
}
__device__ __forceinline__ s16x8 ldfrag(const ushort* p) {
    union { uint4 u; s16x8 s; } cv;
    cv.u = *reinterpret_cast<const uint4*>(p);
    return cv.s;
}
// 8 consecutive f32 -> bf16 hi/lo fragment pair (in-register fragify)
__device__ __forceinline__ void f8_hilo(const float* row, s16x8* hi, s16x8* lo) {
    float4 f0 = *reinterpret_cast<const float4*>(row);
    float4 f1 = *reinterpret_cast<const float4*>(row + 4);
    float f[8] = {f0.x, f0.y, f0.z, f0.w, f1.x, f1.y, f1.z, f1.w};
    union { ushort u[8]; s16x8 s; } H, L;
    #pragma unroll
    for (int j = 0; j < 8; j++) {
        ushort h = f2bf_rne(f[j]);
        H.u[j] = h;
        L.u[j] = f2bf_rne(f[j] - bfbits2f(h));
    }
    *hi = H.s; *lo = L.s;
}

// ---------------------------------------------------------------------------
// prep_all: blocks [0,256) = fragify x + xx; blocks [256,835) = weight frags
//   (q/k/v K=128; wc=[w1x | w1a@wm] K=256 on-the-fly; w2 K=256), b1p, stats=0.
// ---------------------------------------------------------------------------
__global__ __launch_bounds__(256) void prep_all(
    fp xbf, fp wq, fp wk, fp wv, fp wm, fp w1, fp w2, fp bm, fp b1,
    float* xx, ushort* xhiF, ushort* xloF,
    ushort* wqFhi, ushort* wqFlo, ushort* wkFhi, ushort* wkFlo,
    ushort* wvFhi, ushort* wvFlo,
    ushort* wcFhi, ushort* wcFlo, ushort* w2Fhi, ushort* w2Flo,
    float* b1p, float* stats) {
    int t = threadIdx.x;
    if (blockIdx.x < 256) {                 // ---- x frags + xx ----
        __shared__ float xs[16][129];
        __shared__ float xpart[16][17];
        int p0 = blockIdx.x * 16;
        int b = p0 >> 11, n0 = p0 & 2047;
        fp xb = xbf + (size_t)b * 128 * NPT;
        {
            int c = t >> 1, half = t & 1;
            float4 f0 = *reinterpret_cast<const float4*>(xb + (size_t)c * NPT + n0 + half * 8);
            float4 f1 = *reinterpret_cast<const float4*>(xb + (size_t)c * NPT + n0 + half * 8 + 4);
            xs[half * 8 + 0][c] = f0.x; xs[half * 8 + 1][c] = f0.y;
            xs[half * 8 + 2][c] = f0.z; xs[half * 8 + 3][c] = f0.w;
            xs[half * 8 + 4][c] = f1.x; xs[half * 8 + 5][c] = f1.y;
            xs[half * 8 + 6][c] = f1.z; xs[half * 8 + 7][c] = f1.w;
        }
        __syncthreads();
        int p = t & 15, g = t >> 4, c0 = g * 8;
        float f[8];
        #pragma unroll
        for (int j = 0; j < 8; j++) f[j] = xs[p][c0 + j];
        float ps = 0.f;
        #pragma unroll
        for (int j = 0; j < 8; j++) ps += f[j] * f[j];
        xpart[p][g] = ps;
        union { ushort u[8]; uint4 q; } H, L;
        #pragma unroll
        for (int j = 0; j < 8; j++) {
            ushort hi = f2bf_rne(f[j]);
            H.u[j] = hi;
            L.u[j] = f2bf_rne(f[j] - bfbits2f(hi));
        }
        size_t off = ((size_t)blockIdx.x * 4 + (c0 >> 5)) * 512
                   + (size_t)(((((c0 >> 3) & 3) * 16) + p) * 8);
        *reinterpret_cast<uint4*>(xhiF + off) = H.q;
        *reinterpret_cast<uint4*>(xloF + off) = L.q;
        __syncthreads();
        if (t < 16) {
            float s = 0.f;
            #pragma unroll
            for (int gg = 0; gg < 16; gg++) s += xpart[t][gg];
            xx[p0 + t] = s;
        }
        return;
    }
    int wid = (blockIdx.x - 256) * 256 + t;
    if (wid < 49152) {                      // q/k/v frags (K=128)
        int which = wid >> 14, e = wid & 16383;
        int lane = (e >> 3) & 63, j = e & 7, kk = (e >> 9) & 3, nt = e >> 11;
        int n = nt * 16 + (lane & 15);
        int k = kk * 32 + (lane >> 4) * 8 + j;
        fp src = which == 0 ? wq : which == 1 ? wk : wv;
        float v = src[n * 128 + k];
        ushort hi = f2bf_rne(v);
        (which == 0 ? wqFhi : which == 1 ? wkFhi : wvFhi)[e] = hi;
        (which == 0 ? wqFlo : which == 1 ? wkFlo : wvFlo)[e] = f2bf_rne(v - bfbits2f(hi));
    } else if (wid < 114688) {              // wc frags (N=256, K=256)
        int e = wid - 49152;
        int j = e & 7, lane = (e >> 3) & 63, kk = (e >> 9) & 7, nt = e >> 12;
        int n = nt * 16 + (lane & 15);
        int k = kk * 32 + (lane >> 4) * 8 + j;
        float v;
        if (k < 128) {
            v = w1[n * 256 + k];
        } else {                            // W[n][k-128] = w1a@wm on the fly
            int c = k - 128;
            float s = 0.f;
            for (int i = 0; i < 128; i += 4) {
                float4 wr = *reinterpret_cast<const float4*>(w1 + n * 256 + 128 + i);
                s += wr.x * wm[(i + 0) * 128 + c];
                s += wr.y * wm[(i + 1) * 128 + c];
                s += wr.z * wm[(i + 2) * 128 + c];
                s += wr.w * wm[(i + 3) * 128 + c];
            }
            v = s;
        }
        ushort hi = f2bf_rne(v);
        wcFhi[e] = hi;
        wcFlo[e] = f2bf_rne(v - bfbits2f(hi));
    } else if (wid < 147456) {              // w2 frags (N=128, K=256)
        int e = wid - 114688;
        int j = e & 7, lane = (e >> 3) & 63, kk = (e >> 9) & 7, nt = e >> 12;
        int n = nt * 16 + (lane & 15);
        int k = kk * 32 + (lane >> 4) * 8 + j;
        float v = w2[n * 256 + k];
        ushort hi = f2bf_rne(v);
        w2Fhi[e] = hi;
        w2Flo[e] = f2bf_rne(v - bfbits2f(hi));
    } else if (wid < 147712) {              // b1p = b1 + w1a@bm
        int o = wid - 147456;
        float s = b1[o];
        for (int i = 0; i < 128; i++)
            s += w1[o * 256 + 128 + i] * bm[i];
        b1p[o] = s;
    } else {                                // BN stats zero (512)
        stats[wid - 147712] = 0.0f;
    }
}

// ---------------------------------------------------------------------------
// gemm_all: blocks [0,384) = qkv GEMM; [384,1408) = key slab 0;
//           [1408,2432) = key slab 1. All hi/lo bf16 MFMA.
// ---------------------------------------------------------------------------
__global__ __launch_bounds__(256) void gemm_all(
    const ushort* xhiF, const ushort* xloF, const float* xx,
    const ushort* wqFhi, const ushort* wqFlo,
    const ushort* wkFhi, const ushort* wkFlo,
    const ushort* wvFhi, const ushort* wvFlo,
    fp bq, fp bk, fp bv, float* qT, float* kT, float* vT,
    float* key0, float* key1) {
    int t = threadIdx.x, wvi = t >> 6, lane = t & 63;
    if (blockIdx.x < 384) {                 // ---- qkv ----
        int gw = blockIdx.x * 4 + wvi;      // 0..1535
        int rt = gw / 6, rem = gw - rt * 6;
        int mat = rem >> 1, hf = rem & 1;
        const ushort* whi = mat == 0 ? wqFhi : mat == 1 ? wkFhi : wvFhi;
        const ushort* wlo = mat == 0 ? wqFlo : mat == 1 ? wkFlo : wvFlo;
        fp bias    = mat == 0 ? bq : mat == 1 ? bk : bv;
        float* out = mat == 0 ? qT : mat == 1 ? kT : vT;
        f32x4 acc[4];
        #pragma unroll
        for (int j = 0; j < 4; j++) acc[j] = (f32x4){0.f, 0.f, 0.f, 0.f};
        for (int kk = 0; kk < 4; kk++) {
            s16x8 ahi = ldfrag(xhiF + ((size_t)(rt * 4 + kk)) * 512 + lane * 8);
            s16x8 alo = ldfrag(xloF + ((size_t)(rt * 4 + kk)) * 512 + lane * 8);
            #pragma unroll
            for (int j = 0; j < 4; j++) {
                int nt = hf * 4 + j;
                s16x8 bhi = ldfrag(whi + ((size_t)(nt * 4 + kk)) * 512 + lane * 8);
                s16x8 blo = ldfrag(wlo + ((size_t)(nt * 4 + kk)) * 512 + lane * 8);
                acc[j] = __builtin_amdgcn_mfma_f32_16x16x32_bf16(ahi, bhi, acc[j], 0, 0, 0);
                acc[j] = __builtin_amdgcn_mfma_f32_16x16x32_bf16(alo, bhi, acc[j], 0, 0, 0);
                acc[j] = __builtin_amdgcn_mfma_f32_16x16x32_bf16(ahi, blo, acc[j], 0, 0, 0);
            }
        }
        int cl = lane & 15, quad = lane >> 4, p0 = rt * 16;
        #pragma unroll
        for (int j = 0; j < 4; j++) {
            int o = hf * 64 + j * 16 + cl;
            float bvv = bias[o];
            #pragma unroll
            for (int r = 0; r < 4; r++)
                out[(size_t)(p0 + quad * 4 + r) * 128 + o] = acc[j][r] + bvv;
        }
        return;
    }
    // ---- key GEMM ----
    int slab = (blockIdx.x >= 1408) ? 1 : 0;
    int lb = blockIdx.x - 384 - slab * 1024;
    int gw = lb * 4 + wvi;                  // 0..4095
    int rtl = gw >> 5, cs = gw & 31;
    int b = slab;
    int rt = slab * 128 + rtl;
    float* key = slab ? key1 : key0;

    f32x4 acc[4];
    #pragma unroll
    for (int j = 0; j < 4; j++) acc[j] = (f32x4){0.f, 0.f, 0.f, 0.f};
    for (int kk = 0; kk < 4; kk++) {
        s16x8 ahi = ldfrag(xhiF + ((size_t)(rt * 4 + kk)) * 512 + lane * 8);
        s16x8 alo = ldfrag(xloF + ((size_t)(rt * 4 + kk)) * 512 + lane * 8);
        #pragma unroll
        for (int j = 0; j < 4; j++) {
            int ct = b * 128 + cs * 4 + j;
            s16x8 bhi = ldfrag(xhiF + ((size_t)(ct * 4 + kk)) * 512 + lane * 8);
            s16x8 blo = ldfrag(xloF + ((size_t)(ct * 4 + kk)) * 512 + lane * 8);
            acc[j] = __builtin_amdgcn_mfma_f32_16x16x32_bf16(ahi, bhi, acc[j], 0, 0, 0);
            acc[j] = __builtin_amdgcn_mfma_f32_16x16x32_bf16(alo, bhi, acc[j], 0, 0, 0);
            acc[j] = __builtin_amdgcn_mfma_f32_16x16x32_bf16(ahi, blo, acc[j], 0, 0, 0);
        }
    }
    int cl = lane & 15, quad = lane >> 4;
    #pragma unroll
    for (int j = 0; j < 4; j++) {
        int col = cs * 64 + j * 16 + cl;
        float xxv = xx[b * 2048 + col];
        #pragma unroll
        for (int r = 0; r < 4; r++)
            key[(size_t)(rtl * 16 + quad * 4 + r) * 2048 + col] = 2.0f * acc[j][r] - xxv;
    }
}

// ---------------------------------------------------------------------------
// k2b_all: monolithic per-row top-20 with EXACT threshold prefilter.
//   T = 20th-largest of the 64 lane-maxima (bitonic sort) is a provable lower
//   bound on the true 20th-largest (those 20 maxima are >= T), so filtering
//   to values >= T keeps every top-20 member. Survivors (exp. ~24) compacted
//   to LDS; selection runs on <=4 slots/lane. S>256 falls back to full scan.
// ---------------------------------------------------------------------------
#define MERGE(off) { float ov = __shfl_xor(bv, off); int oi = __shfl_xor(bi, off); \
                     if (ov > bv || (ov == bv && oi < bi)) { bv = ov; bi = oi; } }

__global__ __launch_bounds__(256) void k2b_all(
    const float* key0, const float* key1, int* idxbuf) {
    __shared__ float sv[4][256];
    __shared__ int   si[4][256];
    int t = threadIdx.x, w = t >> 6, lane = t & 63;
    int slab = blockIdx.x >> 9;
    int rowl = (blockIdx.x & 511) * 4 + w;
    const float* key = slab ? key1 : key0;
    int rowbase = slab * 2048;
    const float4* kr = reinterpret_cast<const float4*>(key + (size_t)rowl * 2048);
    float rv[32];
    #pragma unroll
    for (int j = 0; j < 8; j++) {
        float4 v = kr[j * 64 + lane];
        rv[j * 4 + 0] = v.x; rv[j * 4 + 1] = v.y;
        rv[j * 4 + 2] = v.z; rv[j * 4 + 3] = v.w;
    }
    // --- lane max (value only) ---
    float lm = rv[0];
    #pragma unroll
    for (int sl = 1; sl < 32; sl++) lm = fmaxf(lm, rv[sl]);
    // --- bitonic sort of lane maxima (ascending across 64 lanes) ---
    float bs = lm;
    #pragma unroll
    for (int k = 2; k <= 64; k <<= 1) {
        #pragma unroll
        for (int j = k >> 1; j > 0; j >>= 1) {
            float o = __shfl_xor(bs, j);
            bool dirDesc = (lane & k) != 0;
            bool upper   = (lane & j) != 0;
            bs = (upper != dirDesc) ? fmaxf(bs, o) : fminf(bs, o);
        }
    }
    float T = __shfl(bs, 44);               // 20th largest lane-max
    // --- survivor count + wave prefix sum ---
    int cnt = 0;
    #pragma unroll
    for (int sl = 0; sl < 32; sl++) cnt += (rv[sl] >= T) ? 1 : 0;
    int inc = cnt;
    #pragma unroll
    for (int off = 1; off < 64; off <<= 1) {
        int o = __shfl_up(inc, off);
        if (lane >= off) inc += o;
    }
    int S = __shfl(inc, 63);
    int pos = inc - cnt;
    bool small = (S <= 256);
    if (small) {                            // compact survivors to LDS
        #pragma unroll
        for (int sl = 0; sl < 32; sl++) {
            if (rv[sl] >= T) {
                sv[w][pos] = rv[sl];
                si[w][pos] = (sl >> 2) * 256 + lane * 4 + (sl & 3);
                pos++;
            }
        }
    }
    __syncthreads();                        // all 256 threads reach this

    if (small) {
        float vl[4]; int il[4];
        #pragma unroll
        for (int s = 0; s < 4; s++) {
            int g = lane + s * 64;
            bool ok = g < S;
            vl[s] = ok ? sv[w][g] : -3.4e38f;
            il[s] = ok ? si[w][g] : 0x7FFFFFFF;
        }
        unsigned removed = 0u;
        for (int iter = 0; iter < KNN; iter++) {
            float bv = -3.4e38f; int bi = 0x7FFFFFFF;
            #pragma unroll
            for (int s = 0; s < 4; s++) {
                bool live = ((removed >> s) & 1u) == 0u;
                if (live && (vl[s] > bv || (vl[s] == bv && il[s] < bi))) {
                    bv = vl[s]; bi = il[s];
                }
            }
            MERGE(32) MERGE(16) MERGE(8) MERGE(4) MERGE(2) MERGE(1)
            if (lane == 0) idxbuf[(size_t)(rowbase + rowl) * KNN + iter] = bi & 2047;
            #pragma unroll
            for (int s = 0; s < 4; s++)     // indices unique: safe removal
                if (il[s] == bi) removed |= 1u << s;
        }
    } else {                                // exact fallback: full 32-slot scan
        unsigned removed = 0u;
        for (int iter = 0; iter < KNN; iter++) {
            float bv = -3.4e38f; int bi = 0;
            #pragma unroll
            for (int sl = 0; sl < 32; sl++) {
                bool live = ((removed >> sl) & 1u) == 0u;
                if (live && rv[sl] > bv) { bv = rv[sl]; bi = (sl >> 2) * 256 + lane * 4 + (sl & 3); }
            }
            MERGE(32) MERGE(16) MERGE(8) MERGE(4) MERGE(2) MERGE(1)
            bi &= 2047;
            if (lane == 0) idxbuf[(size_t)(rowbase + rowl) * KNN + iter] = bi;
            if (((bi >> 2) & 63) == lane) removed |= 1u << ((bi >> 8) * 4 + (bi & 3));
        }
    }
}

// ---------------------------------------------------------------------------
// k3: sparse mutual-KNN attention, 2 points/block; inline mutuality scan.
// ---------------------------------------------------------------------------
__global__ __launch_bounds__(256) void k3_attn(
    fp qT, fp kT, fp vT, const int* idxbuf, float* avT) {
    __shared__ float sbuf[2][KNN * 4];
    __shared__ int   mlist[2][KNN];
    __shared__ int   cnt_s[2];
    int tt = threadIdx.x;
    int half = tt >> 7, t = tt & 127;
    int p = blockIdx.x * 2 + half;
    int b = p >> 11, n = p & 2047;
    int bbase = b * NPT;
    int h = t >> 5;

    if ((tt >> 6) == half * 2) {
        int lane = tt & 63;
        bool fl = false; int m = 0;
        if (lane < KNN) {
            m = idxbuf[(size_t)p * KNN + lane] & 2047;
            const int4* mrow = reinterpret_cast<const int4*>(idxbuf + (size_t)(bbase + m) * KNN);
            int4 r0 = mrow[0], r1 = mrow[1], r2 = mrow[2], r3 = mrow[3], r4 = mrow[4];
            fl = (r0.x == n) || (r0.y == n) || (r0.z == n) || (r0.w == n)
              || (r1.x == n) || (r1.y == n) || (r1.z == n) || (r1.w == n)
              || (r2.x == n) || (r2.y == n) || (r2.z == n) || (r2.w == n)
              || (r3.x == n) || (r3.y == n) || (r3.z == n) || (r3.w == n)
              || (r4.x == n) || (r4.y == n) || (r4.z == n) || (r4.w == n);
        }
        unsigned long long mask = __ballot(fl);
        int pos = __popcll(mask & ((1ull << lane) - 1ull));
        if (fl) mlist[half][pos] = m;
        if (lane == 0) cnt_s[half] = (int)__popcll(mask);
    }
    __syncthreads();

    int cnt = cnt_s[half];
    float qv = qT[(size_t)p * 128 + t];
    for (int jj = 0; jj < cnt; jj++) {
        int m = mlist[half][jj];
        float prod = qv * kT[(size_t)(bbase + m) * 128 + t];
        prod += __shfl_xor(prod, 16);
        prod += __shfl_xor(prod, 8);
        prod += __shfl_xor(prod, 4);
        prod += __shfl_xor(prod, 2);
        prod += __shfl_xor(prod, 1);
        if ((t & 31) == 0) sbuf[half][jj * 4 + h] = prod * 0.17677669529663687f;
    }
    __syncthreads();

    float mx = -3.4e38f;
    for (int j = 0; j < cnt; j++) mx = fmaxf(mx, sbuf[half][j * 4 + h]);
    float den = 0.f;
    for (int j = 0; j < cnt; j++) den += expf(sbuf[half][j * 4 + h] - mx);
    float inv = (cnt > 0) ? (1.0f / den) : 0.0f;
    float acc = 0.f;
    for (int j = 0; j < cnt; j++) {
        float pw = expf(sbuf[half][j * 4 + h] - mx) * inv;
        acc += pw * vT[(size_t)(bbase + mlist[half][j]) * 128 + t];
    }
    avT[(size_t)p * 128 + t] = acc;
}

// ---------------------------------------------------------------------------
// k4b: h = w1x@x + W@av + b1p via MFMA (K=256); epilogue: hbuf + BN stats.
// ---------------------------------------------------------------------------
__global__ __launch_bounds__(256) void k4b_h(
    const ushort* xhiF, const ushort* xloF, const float* avT,
    const ushort* wcFhi, const ushort* wcFlo,
    const float* b1p, float* hbuf, float* stats) {
    int t = threadIdx.x, cs = t >> 6, lane = t & 63;
    int rt = blockIdx.x;                    // 0..255
    int p0 = rt * 16;

    f32x4 acc[4];
    #pragma unroll
    for (int j = 0; j < 4; j++) acc[j] = (f32x4){0.f, 0.f, 0.f, 0.f};

    for (int kk = 0; kk < 8; kk++) {
        s16x8 ahi, alo;
        if (kk < 4) {
            ahi = ldfrag(xhiF + ((size_t)(rt * 4 + kk)) * 512 + lane * 8);
            alo = ldfrag(xloF + ((size_t)(rt * 4 + kk)) * 512 + lane * 8);
        } else {
            const float* arow = avT + (size_t)(p0 + (lane & 15)) * 128
                              + (kk - 4) * 32 + (lane >> 4) * 8;
            f8_hilo(arow, &ahi, &alo);
        }
        #pragma unroll
        for (int j = 0; j < 4; j++) {
            int nt = cs * 4 + j;
            s16x8 bhi = ldfrag(wcFhi + ((size_t)(nt * 8 + kk)) * 512 + lane * 8);
            s16x8 blo = ldfrag(wcFlo + ((size_t)(nt * 8 + kk)) * 512 + lane * 8);
            acc[j] = __builtin_amdgcn_mfma_f32_16x16x32_bf16(ahi, bhi, acc[j], 0, 0, 0);
            acc[j] = __builtin_amdgcn_mfma_f32_16x16x32_bf16(alo, bhi, acc[j], 0, 0, 0);
            acc[j] = __builtin_amdgcn_mfma_f32_16x16x32_bf16(ahi, blo, acc[j], 0, 0, 0);
        }
    }

    int cl = lane & 15, quad = lane >> 4;
    #pragma unroll
    for (int j = 0; j < 4; j++) {
        int o = cs * 64 + j * 16 + cl;
        float bb = b1p[o];
        float s = 0.f, s2 = 0.f;
        #pragma unroll
        for (int r = 0; r < 4; r++) {
            float v = acc[j][r] + bb;
            hbuf[(size_t)(p0 + quad * 4 + r) * 256 + o] = v;
            s += v; s2 += v * v;
        }
        s  += __shfl_xor(s, 16);  s  += __shfl_xor(s, 32);
        s2 += __shfl_xor(s2, 16); s2 += __shfl_xor(s2, 32);
        if (quad == 0) {
            atomicAdd(&stats[o], s);
            atomicAdd(&stats[256 + o], s2);
        }
    }
}

// ---------------------------------------------------------------------------
// k5b: out = w2@relu(BN(h)) + b2 + x via MFMA (K=256), BN in-register.
// ---------------------------------------------------------------------------
__global__ __launch_bounds__(256) void k5b_out(
    const float* hbuf, const float* stats, fp gamma, fp beta,
    const ushort* w2Fhi, const ushort* w2Flo,
    fp b2, fp xbf, float* out) {
    int t = threadIdx.x, wvi = t >> 6, lane = t & 63;
    int rt = blockIdx.x;                    // 0..255
    int p0 = rt * 16;

    f32x4 acc[2];
    acc[0] = (f32x4){0.f, 0.f, 0.f, 0.f};
    acc[1] = (f32x4){0.f, 0.f, 0.f, 0.f};

    for (int kk = 0; kk < 8; kk++) {
        int c0 = kk * 32 + (lane >> 4) * 8;
        const float* hrow = hbuf + (size_t)(p0 + (lane & 15)) * 256 + c0;
        float4 f0 = *reinterpret_cast<const float4*>(hrow);
        float4 f1 = *reinterpret_cast<const float4*>(hrow + 4);
        float4 s0 = *reinterpret_cast<const float4*>(stats + c0);
        float4 s1 = *reinterpret_cast<const float4*>(stats + c0 + 4);
        float4 q0 = *reinterpret_cast<const float4*>(stats + 256 + c0);
        float4 q1 = *reinterpret_cast<const float4*>(stats + 256 + c0 + 4);
        float4 g0 = *reinterpret_cast<const float4*>(gamma + c0);
        float4 g1 = *reinterpret_cast<const float4*>(gamma + c0 + 4);
        float4 e0 = *reinterpret_cast<const float4*>(beta + c0);
        float4 e1 = *reinterpret_cast<const float4*>(beta + c0 + 4);
        float f[8] = {f0.x, f0.y, f0.z, f0.w, f1.x, f1.y, f1.z, f1.w};
        float sm[8] = {s0.x, s0.y, s0.z, s0.w, s1.x, s1.y, s1.z, s1.w};
        float sq[8] = {q0.x, q0.y, q0.z, q0.w, q1.x, q1.y, q1.z, q1.w};
        float gm[8] = {g0.x, g0.y, g0.z, g0.w, g1.x, g1.y, g1.z, g1.w};
        float bt[8] = {e0.x, e0.y, e0.z, e0.w, e1.x, e1.y, e1.z, e1.w};
        union { ushort u[8]; s16x8 s; } H, L;
        #pragma unroll
        for (int j = 0; j < 8; j++) {
            float mu  = sm[j] * (1.0f / 4096.0f);
            float var = fmaxf(sq[j] * (1.0f / 4096.0f) - mu * mu, 0.0f);
            float a    = gm[j] / sqrtf(var + 1e-5f);
            float cadd = bt[j] - mu * a;
            float v = fmaxf(f[j] * a + cadd, 0.0f);
            ushort hi = f2bf_rne(v);
            H.u[j] = hi;
            L.u[j] = f2bf_rne(v - bfbits2f(hi));
        }
        s16x8 ahi = H.s, alo = L.s;
        #pragma unroll
        for (int jj = 0; jj < 2; jj++) {
            int nt = wvi * 2 + jj;
            s16x8 bhi = ldfrag(w2Fhi + ((size_t)(nt * 8 + kk)) * 512 + lane * 8);
            s16x8 blo = ldfrag(w2Flo + ((size_t)(nt * 8 + kk)) * 512 + lane * 8);
            acc[jj] = __builtin_amdgcn_mfma_f32_16x16x32_bf16(ahi, bhi, acc[jj], 0, 0, 0);
            acc[jj] = __builtin_amdgcn_mfma_f32_16x16x32_bf16(alo, bhi, acc[jj], 0, 0, 0);
            acc[jj] = __builtin_amdgcn_mfma_f32_16x16x32_bf16(ahi, blo, acc[jj], 0, 0, 0);
        }
    }
    int cl = lane & 15, quad = lane >> 4;
    int b = p0 >> 11, n0 = p0 & 2047;
    #pragma unroll
    for (int jj = 0; jj < 2; jj++) {
        int o = (wvi * 2 + jj) * 16 + cl;
        float bb = b2[o];
        size_t base = (size_t)b * 128 * NPT + (size_t)o * NPT + n0 + quad * 4;
        float4 xv = *reinterpret_cast<const float4*>(xbf + base);
        float4 ov;
        ov.x = acc[jj][0] + bb + xv.x;
        ov.y = acc[jj][1] + bb + xv.y;
        ov.z = acc[jj][2] + bb + xv.z;
        ov.w = acc[jj][3] + bb + xv.w;
        *reinterpret_cast<float4*>(out + base) = ov;
    }
}

// ---------------------------------------------------------------------------
// Workspace layout (44,978,176 B; observed ws ≈ 268 MB):
//   0        qT 2MB [gemm->k3]   <- hbuf 4MB (k4b->k5b) aliases qT+kT
//   2097152  kT 2MB | 4194304 vT 2MB | 6291456 avT 2MB [k3->k4b]
//   8388608  xx 16KB | 8404992 idxb 320KB | 8732672 stats 2KB | 8734720 b1p 2KB
//   8736768  wq/wk/wv frags 6x32KB
//   8933376  wcFhi/lo 2x128KB | 9195520 w2Fhi/lo 2x64KB
//   9326592  xhiF 1MB | 10375168 xloF 1MB
//   11423744 key0 16MB | 28200960 key1 16MB
// ---------------------------------------------------------------------------
#define WS_FULL 44978176u

extern "C" void kernel_launch(void* const* d_in, const int* in_sizes, int n_in,
                              void* d_out, int out_size, void* d_ws, size_t ws_size,
                              hipStream_t stream) {
    fp desc1 = (fp)d_in[0];
    fp wq = (fp)d_in[1];  fp bq = (fp)d_in[2];
    fp wk = (fp)d_in[3];  fp bk = (fp)d_in[4];
    fp wv = (fp)d_in[5];  fp bv = (fp)d_in[6];
    fp wm = (fp)d_in[7];  fp bm = (fp)d_in[8];
    fp w1 = (fp)d_in[9];  fp b1 = (fp)d_in[10];
    fp gamma = (fp)d_in[11]; fp beta = (fp)d_in[12];
    fp w2 = (fp)d_in[13]; fp b2 = (fp)d_in[14];

    if (ws_size < (size_t)WS_FULL) return;  // all-zero out => ws too small

    char* ws = (char*)d_ws;
    float*  qT    = (float*) (ws + 0);
    float*  kT    = (float*) (ws + 2097152);
    float*  vT    = (float*) (ws + 4194304);
    float*  avT   = (float*) (ws + 6291456);
    float*  xx    = (float*) (ws + 8388608);
    int*    idxb  = (int*)   (ws + 8404992);
    float*  stats = (float*) (ws + 8732672);
    float*  b1p   = (float*) (ws + 8734720);
    ushort* wqFhi = (ushort*)(ws + 8736768);
    ushort* wqFlo = (ushort*)(ws + 8769536);
    ushort* wkFhi = (ushort*)(ws + 8802304);
    ushort* wkFlo = (ushort*)(ws + 8835072);
    ushort* wvFhi = (ushort*)(ws + 8867840);
    ushort* wvFlo = (ushort*)(ws + 8900608);
    ushort* wcFhi = (ushort*)(ws + 8933376);
    ushort* wcFlo = (ushort*)(ws + 9064448);
    ushort* w2Fhi = (ushort*)(ws + 9195520);
    ushort* w2Flo = (ushort*)(ws + 9261056);
    ushort* xhiF  = (ushort*)(ws + 9326592);
    ushort* xloF  = (ushort*)(ws + 10375168);
    float*  key0  = (float*) (ws + 11423744);
    float*  key1  = (float*) (ws + 28200960);
    float*  hbuf  = (float*) (ws + 0);      // aliases qT+kT (dead after k3)

    prep_all<<<835, 256, 0, stream>>>(desc1, wq, wk, wv, wm, w1, w2, bm, b1,
                                      xx, xhiF, xloF,
                                      wqFhi, wqFlo, wkFhi, wkFlo, wvFhi, wvFlo,
                                      wcFhi, wcFlo, w2Fhi, w2Flo, b1p, stats);
    gemm_all<<<2432, 256, 0, stream>>>(xhiF, xloF, xx,
                                       wqFhi, wqFlo, wkFhi, wkFlo, wvFhi, wvFlo,
                                       bq, bk, bv, qT, kT, vT, key0, key1);
    k2b_all<<<1024, 256, 0, stream>>>(key0, key1, idxb);
    k3_attn<<<2048, 256, 0, stream>>>(qT, kT, vT, idxb, avT);
    k4b_h<<<256, 256, 0, stream>>>(xhiF, xloF, avT, wcFhi, wcFlo,
                                   b1p, hbuf, stats);
    k5b_out<<<256, 256, 0, stream>>>(hbuf, stats, gamma, beta, w2Fhi, w2Flo,
                                     b2, desc1, (float*)d_out);
}